// Round 2
// baseline (784.483 us; speedup 1.0000x reference)
//
#include <hip/hip_runtime.h>
#include <hip/hip_fp16.h>

#define RANK   64
#define VOCAB  32768
#define BATCH  2048
#define SEQLEN 256

typedef __attribute__((ext_vector_type(8))) unsigned short ushort8; // 16B = 8 halves

// ---------------------------------------------------------------------------
// Kernel 1: ws[v][g][s][k] = (half)( core[8g+k][v][s]^2 )
// One ushort8 (16B) per thread. For fixed (v,g,k), consecutive s -> coalesced.
// ---------------------------------------------------------------------------
__global__ __launch_bounds__(256) void squash_kernel(const float* __restrict__ core,
                                                     ushort8* __restrict__ ws8) {
    int o = blockIdx.x * 256 + threadIdx.x;
    int v = o >> 9;
    int g = (o >> 6) & 7;
    int s = o & 63;
    ushort8 outv;
#pragma unroll
    for (int k = 0; k < 8; ++k) {
        int r = g * 8 + k;
        float c = core[((size_t)r * VOCAB + v) * RANK + s];
        __half h = __float2half(c * c);
        outv[k] = __builtin_bit_cast(unsigned short, h);
    }
    ws8[o] = outv;
}

// ---------------------------------------------------------------------------
// One recurrence step: lane s computes l_new[s] = sum_r l[r] * M[r,s].
// buf[g] holds M[8g..8g+7, lane] as 8 halves. l[r] broadcast via v_readlane
// with literal lane index (fully unrolled).
// ---------------------------------------------------------------------------
__device__ __forceinline__ float mps_step(float l, const ushort8 buf[8]) {
    float acc[4] = {0.f, 0.f, 0.f, 0.f};
#pragma unroll
    for (int g = 0; g < 8; ++g) {
        ushort8 m = buf[g];
#pragma unroll
        for (int k = 0; k < 8; ++k) {
            const int r = g * 8 + k;
            float lr = __uint_as_float(
                __builtin_amdgcn_readlane(__float_as_uint(l), r));
            unsigned short ub = m[k];
            __half h = __builtin_bit_cast(__half, ub);
            float mv = __half2float(h);
            acc[k & 3] = fmaf(lr, mv, acc[k & 3]);
        }
    }
    return (acc[0] + acc[1]) + (acc[2] + acc[3]);
}

__device__ __forceinline__ void load_buf(ushort8 (&B)[8], const ushort8* __restrict__ ws8,
                                         int tok, int lane) {
    const ushort8* p = ws8 + (size_t)tok * 512 + lane;
#pragma unroll
    for (int g = 0; g < 8; ++g) B[g] = p[g * 64];
}

// ---------------------------------------------------------------------------
// Kernel 2: one wave per batch element. Whole token row pre-loaded into
// registers (no memory ops on the token path inside the loop -> no vmcnt(0)
// drains). 4-buffer rotating prefetch, depth-3 in flight (24 KB/wave).
// ---------------------------------------------------------------------------
__global__ __launch_bounds__(256) void mps_fp16_kernel(const int* __restrict__ y,
                                                       const float* __restrict__ alpha,
                                                       const float* __restrict__ beta,
                                                       const ushort8* __restrict__ ws8,
                                                       float* __restrict__ out) {
    int b    = (blockIdx.x * 256 + threadIdx.x) >> 6;
    int lane = threadIdx.x & 63;
    const int* yrow = y + (size_t)b * SEQLEN;

    // lane L holds tokens y[b, 64c + L] for c = 0..3
    int yr[4];
#pragma unroll
    for (int c = 0; c < 4; ++c) yr[c] = yrow[c * 64 + lane];

    float a = alpha[lane];
    float l = a * a;

    ushort8 buf[4][8];

    // prefetch steps 0..3
#pragma unroll
    for (int j = 0; j < 4; ++j) {
        int tok = __builtin_amdgcn_readlane(yr[0], j);
        load_buf(buf[j], ws8, tok, lane);
    }

#pragma unroll
    for (int c = 0; c < 4; ++c) {
        int ycur = yr[c];
        int ynxt = yr[(c + 1) & 3];   // c==3: wraps to yr[0] -> valid tokens, never consumed
#pragma unroll 1
        for (int k = 0; k < 16; ++k) {
#pragma unroll
            for (int j = 0; j < 4; ++j) {
                l = mps_step(l, buf[j]);
                int kk   = 4 * k + 4 + j;           // token index (within chunk) to prefetch
                int ysel = (kk < 64) ? ycur : ynxt; // uniform select, then one readlane
                int tok  = __builtin_amdgcn_readlane(ysel, kk & 63);
                load_buf(buf[j], ws8, tok, lane);
            }
        }
    }

    float bb = beta[lane];
    float v  = l * bb * bb;
#pragma unroll
    for (int off = 32; off > 0; off >>= 1) v += __shfl_xor(v, off, 64);
    if (lane == 0) out[b] = v;
}

// ---------------------------------------------------------------------------
// Fallback (exact f32, direct gather from core) if ws is too small.
// ---------------------------------------------------------------------------
__global__ __launch_bounds__(256) void mps_f32_kernel(const int* __restrict__ y,
                                                      const float* __restrict__ alpha,
                                                      const float* __restrict__ beta,
                                                      const float* __restrict__ core,
                                                      float* __restrict__ out) {
    int b    = (blockIdx.x * 256 + threadIdx.x) >> 6;
    int lane = threadIdx.x & 63;
    const int* yrow = y + (size_t)b * SEQLEN;

    float a = alpha[lane];
    float l = a * a;

#pragma unroll 1
    for (int t = 0; t < SEQLEN; ++t) {
        int tok = __builtin_amdgcn_readfirstlane(yrow[t]);
        const float* p = core + (size_t)tok * RANK + lane;
        float acc[4] = {0.f, 0.f, 0.f, 0.f};
#pragma unroll
        for (int r = 0; r < RANK; ++r) {
            float m  = p[(size_t)r * (VOCAB * RANK)];
            float lr = __uint_as_float(
                __builtin_amdgcn_readlane(__float_as_uint(l), r));
            acc[r & 3] = fmaf(lr, m * m, acc[r & 3]);
        }
        l = (acc[0] + acc[1]) + (acc[2] + acc[3]);
    }

    float bb = beta[lane];
    float v  = l * bb * bb;
#pragma unroll
    for (int off = 32; off > 0; off >>= 1) v += __shfl_xor(v, off, 64);
    if (lane == 0) out[b] = v;
}

extern "C" void kernel_launch(void* const* d_in, const int* in_sizes, int n_in,
                              void* d_out, int out_size, void* d_ws, size_t ws_size,
                              hipStream_t stream) {
    const int*   y     = (const int*)d_in[0];
    const float* alpha = (const float*)d_in[1];
    const float* beta  = (const float*)d_in[2];
    const float* core  = (const float*)d_in[3];
    float*       out   = (float*)d_out;

    const size_t need = (size_t)VOCAB * RANK * RANK * sizeof(unsigned short); // 256 MiB

    if (ws_size >= need) {
        int chunks = VOCAB * 8 * 64;
        squash_kernel<<<chunks / 256, 256, 0, stream>>>(core, (ushort8*)d_ws);
        mps_fp16_kernel<<<(BATCH * 64) / 256, 256, 0, stream>>>(
            y, alpha, beta, (const ushort8*)d_ws, out);
    } else {
        mps_f32_kernel<<<(BATCH * 64) / 256, 256, 0, stream>>>(
            y, alpha, beta, core, out);
    }
}

// Round 4
// 777.580 us; speedup vs baseline: 1.0089x; 1.0089x over previous
//
#include <hip/hip_runtime.h>
#include <hip/hip_fp16.h>

#define RANK   64
#define VOCAB  32768
#define BATCH  2048
#define SEQLEN 256

typedef __attribute__((ext_vector_type(8))) unsigned short ushort8; // 16B = 8 halves

// ---------------------------------------------------------------------------
// Kernel 1: ws[v][g][s][k] = (half)( core[8g+k][v][s]^2 )
// One ushort8 (16B) per thread. For fixed (v,g,k), consecutive s -> coalesced.
// ---------------------------------------------------------------------------
__global__ __launch_bounds__(256) void squash_kernel(const float* __restrict__ core,
                                                     ushort8* __restrict__ ws8) {
    int o = blockIdx.x * 256 + threadIdx.x;
    int v = o >> 9;
    int g = (o >> 6) & 7;
    int s = o & 63;
    ushort8 outv;
#pragma unroll
    for (int k = 0; k < 8; ++k) {
        int r = g * 8 + k;
        float c = core[((size_t)r * VOCAB + v) * RANK + s];
        __half h = __float2half(c * c);
        outv[k] = __builtin_bit_cast(unsigned short, h);
    }
    ws8[o] = outv;
}

// ---------------------------------------------------------------------------
// One recurrence step: lane s computes l_new[s] = sum_r l[r] * M[r,s].
// buf[g] holds M[8g..8g+7, lane] as 8 halves; l[r] broadcast via v_readlane
// with literal lane index (fully unrolled).
// ---------------------------------------------------------------------------
__device__ __forceinline__ float mps_step(float l, const ushort8 buf[8]) {
    float acc[4] = {0.f, 0.f, 0.f, 0.f};
#pragma unroll
    for (int g = 0; g < 8; ++g) {
        ushort8 m = buf[g];
#pragma unroll
        for (int k = 0; k < 8; ++k) {
            const int r = g * 8 + k;
            float lr = __uint_as_float(
                __builtin_amdgcn_readlane(__float_as_uint(l), r));
            __half h = __builtin_bit_cast(__half, (unsigned short)m[k]);
            acc[k & 3] = fmaf(lr, __half2float(h), acc[k & 3]);
        }
    }
    return (acc[0] + acc[1]) + (acc[2] + acc[3]);
}

__device__ __forceinline__ void load_buf(ushort8 (&B)[8], const ushort8* __restrict__ ws8,
                                         int tok, int lane) {
    const ushort8* p = ws8 + (size_t)tok * 512 + lane;
#pragma unroll
    for (int g = 0; g < 8; ++g) B[g] = p[g * 64];
}

// ---------------------------------------------------------------------------
// Kernel 2: one wave per batch element. Token row held in lane registers
// (no memory ops on the token path -> no vmcnt(0) drains). 4 rotating
// register buffers, issue 3 steps ahead. Pipeline order pinned with
// sched_barrier(0); waitcnts are compiler-inserted (counted, correct by
// construction). __launch_bounds__(256,1) relaxes the VGPR budget so all
// 4 buffers (128 VGPRs) stay live instead of being sunk to their use.
// ---------------------------------------------------------------------------
__global__ __launch_bounds__(256, 1) void mps_fp16_kernel(const int* __restrict__ y,
                                                          const float* __restrict__ alpha,
                                                          const float* __restrict__ beta,
                                                          const ushort8* __restrict__ ws8,
                                                          float* __restrict__ out) {
    int b    = (blockIdx.x * 256 + threadIdx.x) >> 6;
    int lane = threadIdx.x & 63;
    const int* yrow = y + (size_t)b * SEQLEN;

    // lane L holds tokens y[b, 64c + L]
    int yr0 = yrow[0 * 64 + lane];
    int yr1 = yrow[1 * 64 + lane];
    int yr2 = yrow[2 * 64 + lane];
    int yr3 = yrow[3 * 64 + lane];

    float a  = alpha[lane];
    float bb = beta[lane];
    float l  = a * a;

    ushort8 buf[4][8];

    // prologue: issue steps 0,1,2
#pragma unroll
    for (int j = 0; j < 3; ++j) {
        int tok = __builtin_amdgcn_readlane(yr0, j);
        load_buf(buf[j], ws8, tok, lane);
    }

#pragma unroll
    for (int c = 0; c < 4; ++c) {
        int ycur = (c == 0) ? yr0 : (c == 1) ? yr1 : (c == 2) ? yr2 : yr3;
        int ynxt = (c == 0) ? yr1 : (c == 1) ? yr2 : (c == 2) ? yr3 : yr0;
#pragma unroll 1
        for (int k = 0; k < 16; ++k) {
#pragma unroll
            for (int j = 0; j < 4; ++j) {
                // consume step s = 64c + 4k + j; prefetch s+3 into buf[(j+3)&3]
                int kk   = 4 * k + j + 3;
                int ysel = (kk < 64) ? ycur : ynxt; // c==3 wraps: issued, never consumed
                int tok  = __builtin_amdgcn_readlane(ysel, kk & 63);
                load_buf(buf[(j + 3) & 3], ws8, tok, lane);
                __builtin_amdgcn_sched_barrier(0); // loads stay above, consume below
                l = mps_step(l, buf[j]);
                __builtin_amdgcn_sched_barrier(0); // next j's loads can't hoist
            }
        }
    }

    float v = l * bb * bb;
#pragma unroll
    for (int off = 32; off > 0; off >>= 1) v += __shfl_xor(v, off, 64);
    if (lane == 0) out[b] = v;
}

// ---------------------------------------------------------------------------
// Fallback (exact f32, direct gather from core) if ws is too small.
// ---------------------------------------------------------------------------
__global__ __launch_bounds__(256) void mps_f32_kernel(const int* __restrict__ y,
                                                      const float* __restrict__ alpha,
                                                      const float* __restrict__ beta,
                                                      const float* __restrict__ core,
                                                      float* __restrict__ out) {
    int b    = (blockIdx.x * 256 + threadIdx.x) >> 6;
    int lane = threadIdx.x & 63;
    const int* yrow = y + (size_t)b * SEQLEN;

    float a = alpha[lane];
    float l = a * a;

#pragma unroll 1
    for (int t = 0; t < SEQLEN; ++t) {
        int tok = __builtin_amdgcn_readfirstlane(yrow[t]);
        const float* p = core + (size_t)tok * RANK + lane;
        float acc[4] = {0.f, 0.f, 0.f, 0.f};
#pragma unroll
        for (int r = 0; r < RANK; ++r) {
            float m  = p[(size_t)r * (VOCAB * RANK)];
            float lr = __uint_as_float(
                __builtin_amdgcn_readlane(__float_as_uint(l), r));
            acc[r & 3] = fmaf(lr, m * m, acc[r & 3]);
        }
        l = (acc[0] + acc[1]) + (acc[2] + acc[3]);
    }

    float bb = beta[lane];
    float v  = l * bb * bb;
#pragma unroll
    for (int off = 32; off > 0; off >>= 1) v += __shfl_xor(v, off, 64);
    if (lane == 0) out[b] = v;
}

extern "C" void kernel_launch(void* const* d_in, const int* in_sizes, int n_in,
                              void* d_out, int out_size, void* d_ws, size_t ws_size,
                              hipStream_t stream) {
    const int*   y     = (const int*)d_in[0];
    const float* alpha = (const float*)d_in[1];
    const float* beta  = (const float*)d_in[2];
    const float* core  = (const float*)d_in[3];
    float*       out   = (float*)d_out;

    const size_t need = (size_t)VOCAB * RANK * RANK * sizeof(unsigned short); // 256 MiB

    if (ws_size >= need) {
        int chunks = VOCAB * 8 * 64;
        squash_kernel<<<chunks / 256, 256, 0, stream>>>(core, (ushort8*)d_ws);
        mps_fp16_kernel<<<(BATCH * 64) / 256, 256, 0, stream>>>(
            y, alpha, beta, (const ushort8*)d_ws, out);
    } else {
        mps_f32_kernel<<<(BATCH * 64) / 256, 256, 0, stream>>>(
            y, alpha, beta, core, out);
    }
}